// Round 1
// baseline (7608.789 us; speedup 1.0000x reference)
//
#include <hip/hip_runtime.h>

#define NB 16
#define HH 256
#define WW 256
#define NPIX (HH*WW)

// ---------------------------------------------------------------------------
// prepack: wfb [64][64][3][3] -> wpB [tap][cin][cout64]
//          wfc [81][64][3][3] -> wpC [tap][cin][cout81]
// so that inner-loop weight reads are wave-uniform & cout-contiguous (s_load).
// ---------------------------------------------------------------------------
__global__ __launch_bounds__(256) void prepack_kernel(
    const float* __restrict__ wfb, const float* __restrict__ wfc,
    float* __restrict__ wpB, float* __restrict__ wpC)
{
    int i = blockIdx.x * 256 + threadIdx.x;
    if (i < 64 * 64 * 9) {
        int tap = i % 9, cin = (i / 9) & 63, cout = i / (9 * 64);
        wpB[(tap * 64 + cin) * 64 + cout] = wfb[i];
    }
    if (i < 81 * 64 * 9) {
        int tap = i % 9, cin = (i / 9) & 63, cout = i / (9 * 64);
        wpC[(tap * 64 + cin) * 81 + cout] = wfc[i];
    }
}

// ---------------------------------------------------------------------------
// branch: feat[b][br] = conv1b(relu(conv1a(in))) fused, 16x16 tile/block.
// hidden (64ch, tile+1 halo) staged in LDS channel-last [324][68].
// ---------------------------------------------------------------------------
__global__ __launch_bounds__(256) void branch_kernel(
    const float* __restrict__ x, const float* __restrict__ g,
    const float* __restrict__ w1a, const float* __restrict__ b1a,
    const float* __restrict__ w1b, const float* __restrict__ b1b,
    const float* __restrict__ w2a, const float* __restrict__ b2a,
    const float* __restrict__ w2b, const float* __restrict__ b2b,
    float* __restrict__ feat)
{
    extern __shared__ float smem[];
    float* ht = smem;              // [324][68]
    float* xt = ht + 324 * 68;     // [20][20]
    float* wa = xt + 400;          // [9][64]  (tap-major)
    float* wb = wa + 576;          // [9][64]
    float* ba = wb + 576;          // [64]

    const int tid = threadIdx.x;
    const int tx = tid & 15, ty = tid >> 4;
    const int x0 = blockIdx.x * 16, y0 = blockIdx.y * 16;
    const int b = blockIdx.z >> 1, br = blockIdx.z & 1;

    const float* in = (br ? g : x) + (size_t)b * NPIX;
    const float* wA = br ? w2a : w1a;
    const float* wB = br ? w2b : w1b;
    const float* bA = br ? b2a : b1a;
    const float* bB = br ? b2b : b1b;

    // load weights (tap-major repack in LDS)
    for (int t = tid; t < 576; t += 256) {
        int c = t / 9, tap = t % 9;
        wa[tap * 64 + c] = wA[t];
        wb[tap * 64 + c] = wB[t];
    }
    if (tid < 64) ba[tid] = bA[tid];

    // load input tile with halo 2 (20x20), zero-padded
    for (int t = tid; t < 400; t += 256) {
        int r = t / 20, c = t % 20;
        int gy = y0 - 2 + r, gx = x0 - 2 + c;
        xt[t] = ((unsigned)gy < (unsigned)HH && (unsigned)gx < (unsigned)WW)
                    ? in[gy * WW + gx] : 0.f;
    }
    __syncthreads();

    // stage 1: hidden = relu(conv1a) over 18x18 region, 64 ch
    // item = (pixel p, channel-quad cq); 16 lanes share p -> xt broadcast
    for (int t = tid; t < 324 * 16; t += 256) {
        int p = t >> 4, cq = t & 15, c0 = cq * 4;
        int py = p / 18, px = p % 18;
        float a0 = ba[c0], a1 = ba[c0 + 1], a2 = ba[c0 + 2], a3 = ba[c0 + 3];
        #pragma unroll
        for (int u = 0; u < 3; u++)
            #pragma unroll
            for (int v = 0; v < 3; v++) {
                float xv = xt[(py + u) * 20 + px + v];
                int wi = (u * 3 + v) * 64 + c0;
                a0 += xv * wa[wi];
                a1 += xv * wa[wi + 1];
                a2 += xv * wa[wi + 2];
                a3 += xv * wa[wi + 3];
            }
        float* hp = &ht[p * 68 + c0];
        hp[0] = fmaxf(a0, 0.f); hp[1] = fmaxf(a1, 0.f);
        hp[2] = fmaxf(a2, 0.f); hp[3] = fmaxf(a3, 0.f);
    }
    __syncthreads();

    // stage 2: feat = conv1b(hidden) at this thread's pixel
    float acc = bB[0];
    #pragma unroll
    for (int u = 0; u < 3; u++)
        #pragma unroll
        for (int v = 0; v < 3; v++) {
            int base = ((ty + u) * 18 + (tx + v)) * 68;
            int wi = (u * 3 + v) * 64;
            #pragma unroll
            for (int cq = 0; cq < 16; cq++) {
                float4 h4 = *(const float4*)&ht[base + cq * 4];
                acc += h4.x * wb[wi + cq * 4]     + h4.y * wb[wi + cq * 4 + 1]
                     + h4.z * wb[wi + cq * 4 + 2] + h4.w * wb[wi + cq * 4 + 3];
            }
        }
    feat[((size_t)(b * 2 + br)) * NPIX + (y0 + ty) * WW + (x0 + tx)] = acc;
}

// ---------------------------------------------------------------------------
// wfa: h1 = relu(conv3x3(feat, wfa)), 2 -> 64 ch. h1 layout [ci][pix][64].
// ---------------------------------------------------------------------------
__global__ __launch_bounds__(256) void wfa_kernel(
    const float* __restrict__ feat, const float* __restrict__ wfa,
    const float* __restrict__ bfa, float* __restrict__ h1, int b0)
{
    __shared__ float ft[2 * 324];
    const int tid = threadIdx.x;
    const int tx = tid & 15, ty = tid >> 4;
    const int x0 = blockIdx.x * 16, y0 = blockIdx.y * 16;
    const int ci = blockIdx.z, b = b0 + ci;

    for (int t = tid; t < 648; t += 256) {
        int cin = t / 324, p = t % 324;
        int py = p / 18, px = p % 18;
        int gy = y0 - 1 + py, gx = x0 - 1 + px;
        ft[t] = ((unsigned)gy < (unsigned)HH && (unsigned)gx < (unsigned)WW)
                    ? feat[((size_t)(b * 2 + cin)) * NPIX + gy * WW + gx] : 0.f;
    }
    __syncthreads();

    float* h1p = h1 + (size_t)ci * (64 * NPIX)
               + ((size_t)((y0 + ty) * WW + x0 + tx)) * 64;

    for (int cog = 0; cog < 8; cog++) {
        float acc[8];
        #pragma unroll
        for (int j = 0; j < 8; j++) acc[j] = bfa[cog * 8 + j];
        for (int cin = 0; cin < 2; cin++) {
            #pragma unroll
            for (int u = 0; u < 3; u++)
                #pragma unroll
                for (int v = 0; v < 3; v++) {
                    float fv = ft[cin * 324 + (ty + u) * 18 + tx + v];
                    #pragma unroll
                    for (int j = 0; j < 8; j++)
                        acc[j] += fv * wfa[((cog * 8 + j) * 2 + cin) * 9 + u * 3 + v];
                }
        }
        #pragma unroll
        for (int j = 0; j < 8; j++) h1p[cog * 8 + j] = fmaxf(acc[j], 0.f);
    }
}

// ---------------------------------------------------------------------------
// wfb: h2 = relu(conv3x3(h1, wfb)), 64 -> 64. LDS tile [324][68] fp32,
// float4 channel reads, 8-wide cout register blocking, s_load weights.
// ---------------------------------------------------------------------------
__global__ __launch_bounds__(256) void wfb_kernel(
    const float* __restrict__ h1, const float* __restrict__ wpB,
    const float* __restrict__ bfb, float* __restrict__ h2)
{
    extern __shared__ float smem[];
    float* ht = smem; // [324][68]
    const int tid = threadIdx.x;
    const int tx = tid & 15, ty = tid >> 4;
    const int x0 = blockIdx.x * 16, y0 = blockIdx.y * 16;
    const int ci = blockIdx.z;

    const float* h1b = h1 + (size_t)ci * (64 * NPIX);
    for (int t = tid; t < 324 * 16; t += 256) {
        int p = t >> 4, cq = t & 15;
        int py = p / 18, px = p % 18;
        int gy = y0 - 1 + py, gx = x0 - 1 + px;
        float4 v = make_float4(0.f, 0.f, 0.f, 0.f);
        if ((unsigned)gy < (unsigned)HH && (unsigned)gx < (unsigned)WW)
            v = *(const float4*)&h1b[((size_t)(gy * WW + gx)) * 64 + cq * 4];
        *(float4*)&ht[p * 68 + cq * 4] = v;
    }
    __syncthreads();

    float* h2p = h2 + (size_t)ci * (64 * NPIX)
               + ((size_t)((y0 + ty) * WW + x0 + tx)) * 64;

    for (int cog = 0; cog < 8; cog++) {
        float acc[8];
        #pragma unroll
        for (int j = 0; j < 8; j++) acc[j] = bfb[cog * 8 + j];
        for (int tap = 0; tap < 9; tap++) {
            int u = tap / 3, v = tap - u * 3;
            const int base = ((ty + u) * 18 + (tx + v)) * 68;
            const float* wp0 = wpB + (tap * 64) * 64 + cog * 8;
            #pragma unroll 4
            for (int cq = 0; cq < 16; cq++) {
                float4 h4 = *(const float4*)&ht[base + cq * 4];
                const float* wp = wp0 + cq * 4 * 64;
                #pragma unroll
                for (int j = 0; j < 8; j++)
                    acc[j] += h4.x * wp[j]       + h4.y * wp[64 + j]
                            + h4.z * wp[128 + j] + h4.w * wp[192 + j];
            }
        }
        #pragma unroll
        for (int j = 0; j < 8; j++) h2p[cog * 8 + j] = fmaxf(acc[j], 0.f);
    }
}

// ---------------------------------------------------------------------------
// wfc + softmax + patch-apply fused: never materializes filt [B,81,H,W].
// Online softmax over 9 groups (one 9x9 filter row per group).
// ---------------------------------------------------------------------------
__global__ __launch_bounds__(256) void wfc_apply_kernel(
    const float* __restrict__ h2, const float* __restrict__ wpC,
    const float* __restrict__ bfc, const float* __restrict__ x,
    float* __restrict__ out, int b0)
{
    extern __shared__ float smem[];
    float* ht  = smem;             // [324][68]
    float* xts = ht + 324 * 68;    // [24][24]
    const int tid = threadIdx.x;
    const int tx = tid & 15, ty = tid >> 4;
    const int x0 = blockIdx.x * 16, y0 = blockIdx.y * 16;
    const int ci = blockIdx.z, b = b0 + ci;

    const float* h2b = h2 + (size_t)ci * (64 * NPIX);
    for (int t = tid; t < 324 * 16; t += 256) {
        int p = t >> 4, cq = t & 15;
        int py = p / 18, px = p % 18;
        int gy = y0 - 1 + py, gx = x0 - 1 + px;
        float4 v = make_float4(0.f, 0.f, 0.f, 0.f);
        if ((unsigned)gy < (unsigned)HH && (unsigned)gx < (unsigned)WW)
            v = *(const float4*)&h2b[((size_t)(gy * WW + gx)) * 64 + cq * 4];
        *(float4*)&ht[p * 68 + cq * 4] = v;
    }
    const float* xb = x + (size_t)b * NPIX;
    for (int t = tid; t < 576; t += 256) {
        int r = t / 24, c = t % 24;
        int gy = y0 - 4 + r, gx = x0 - 4 + c;
        xts[t] = ((unsigned)gy < (unsigned)HH && (unsigned)gx < (unsigned)WW)
                     ? xb[gy * WW + gx] : 0.f;
    }
    __syncthreads();

    float m = -1e30f, s = 0.f, o = 0.f;
    for (int grp = 0; grp < 9; grp++) {   // filter row = couts grp*9 .. grp*9+8
        float acc[9];
        #pragma unroll
        for (int k = 0; k < 9; k++) acc[k] = bfc[grp * 9 + k];
        for (int tap = 0; tap < 9; tap++) {
            int u = tap / 3, v = tap - u * 3;
            const int base = ((ty + u) * 18 + (tx + v)) * 68;
            const float* wp0 = wpC + (tap * 64) * 81 + grp * 9;
            #pragma unroll 4
            for (int cq = 0; cq < 16; cq++) {
                float4 h4 = *(const float4*)&ht[base + cq * 4];
                const float* wp = wp0 + cq * 4 * 81;
                #pragma unroll
                for (int k = 0; k < 9; k++)
                    acc[k] += h4.x * wp[k]        + h4.y * wp[81 + k]
                            + h4.z * wp[162 + k]  + h4.w * wp[243 + k];
            }
        }
        float gm = acc[0];
        #pragma unroll
        for (int k = 1; k < 9; k++) gm = fmaxf(gm, acc[k]);
        float nm = fmaxf(m, gm);
        float sc = __expf(m - nm);
        s *= sc; o *= sc;
        #pragma unroll
        for (int k = 0; k < 9; k++) {
            float e = __expf(acc[k] - nm);
            s += e;
            o += e * xts[(ty + grp) * 24 + tx + k];
        }
        m = nm;
    }
    out[(size_t)b * NPIX + (y0 + ty) * WW + (x0 + tx)] = o / s;
}

// ---------------------------------------------------------------------------
extern "C" void kernel_launch(void* const* d_in, const int* in_sizes, int n_in,
                              void* d_out, int out_size, void* d_ws, size_t ws_size,
                              hipStream_t stream)
{
    const float* x   = (const float*)d_in[0];
    const float* g   = (const float*)d_in[1];
    const float* w1a = (const float*)d_in[2];  const float* b1a = (const float*)d_in[3];
    const float* w1b = (const float*)d_in[4];  const float* b1b = (const float*)d_in[5];
    const float* w2a = (const float*)d_in[6];  const float* b2a = (const float*)d_in[7];
    const float* w2b = (const float*)d_in[8];  const float* b2b = (const float*)d_in[9];
    const float* wfa = (const float*)d_in[10]; const float* bfa = (const float*)d_in[11];
    const float* wfb = (const float*)d_in[12]; const float* bfb = (const float*)d_in[13];
    const float* wfc = (const float*)d_in[14]; const float* bfc = (const float*)d_in[15];
    float* out = (float*)d_out;

    // workspace layout (floats)
    float* feat = (float*)d_ws;                 // 16*2*65536   = 2,097,152
    float* wpB  = feat + 2097152;               // 9*64*64      = 36,864
    float* wpC  = wpB + 36864;                  // 9*64*81      = 46,656
    float* h1   = wpC + 46656;                  // nc*64*65536 each

    size_t availf = ws_size / 4;
    size_t fixedf = 2097152 + 36864 + 46656;
    int nc = 1;
    const int cand[5] = {16, 8, 4, 2, 1};
    for (int i = 0; i < 5; i++) {
        if (fixedf + (size_t)cand[i] * 2ull * 64 * NPIX <= availf) { nc = cand[i]; break; }
    }
    float* h2 = h1 + (size_t)nc * 64 * NPIX;

    prepack_kernel<<<dim3(183), 256, 0, stream>>>(wfb, wfc, wpB, wpC);

    size_t shA = (size_t)(324 * 68 + 400 + 576 + 576 + 64) * 4;
    branch_kernel<<<dim3(16, 16, 32), 256, shA, stream>>>(
        x, g, w1a, b1a, w1b, b1b, w2a, b2a, w2b, b2b, feat);

    size_t shC = (size_t)(324 * 68) * 4;
    size_t shD = (size_t)(324 * 68 + 576) * 4;
    for (int bb0 = 0; bb0 < NB; bb0 += nc) {
        int cn = (NB - bb0) < nc ? (NB - bb0) : nc;
        wfa_kernel<<<dim3(16, 16, cn), 256, 0, stream>>>(feat, wfa, bfa, h1, bb0);
        wfb_kernel<<<dim3(16, 16, cn), 256, shC, stream>>>(h1, wpB, bfb, h2);
        wfc_apply_kernel<<<dim3(16, 16, cn), 256, shD, stream>>>(h2, wpC, bfc, x, out, bb0);
    }
}

// Round 2
// 1032.410 us; speedup vs baseline: 7.3699x; 7.3699x over previous
//
#include <hip/hip_runtime.h>

#define NB 16
#define HH 256
#define WW 256
#define NPIX (HH*WW)

typedef _Float16 f16;
typedef _Float16 f16x8 __attribute__((ext_vector_type(8)));
typedef float f32x4 __attribute__((ext_vector_type(4)));

// ---------------------------------------------------------------------------
// prepack: weights -> f16, k = tap*64+cin ordering, cout-major rows.
// wpA [64][32] (k = cin*9+tap, zero-pad k>=18), wpB [64][576], wpC [96][576].
// ---------------------------------------------------------------------------
__global__ __launch_bounds__(256) void prepack_kernel(
    const float* __restrict__ wfa, const float* __restrict__ wfb,
    const float* __restrict__ wfc,
    f16* __restrict__ wpA, f16* __restrict__ wpB, f16* __restrict__ wpC)
{
    int i = blockIdx.x * 256 + threadIdx.x;
    if (i < 64 * 32) {
        int c = i >> 5, k = i & 31;
        wpA[i] = (f16)(k < 18 ? wfa[c * 18 + k] : 0.f);
    }
    if (i < 64 * 576) {
        int c = i / 576, k = i % 576;
        int tap = k >> 6, cin = k & 63;
        wpB[i] = (f16)wfb[(c * 64 + cin) * 9 + tap];
    }
    if (i < 96 * 576) {
        int c = i / 576, k = i % 576;
        int tap = k >> 6, cin = k & 63;
        wpC[i] = (f16)(c < 81 ? wfc[(c * 64 + cin) * 9 + tap] : 0.f);
    }
}

// ---------------------------------------------------------------------------
// branch: feat[b][br] = conv1b(relu(conv1a(in))) fused, 16x16 tile/block.
// (unchanged from the passing round-1 version)
// ---------------------------------------------------------------------------
__global__ __launch_bounds__(256) void branch_kernel(
    const float* __restrict__ x, const float* __restrict__ g,
    const float* __restrict__ w1a, const float* __restrict__ b1a,
    const float* __restrict__ w1b, const float* __restrict__ b1b,
    const float* __restrict__ w2a, const float* __restrict__ b2a,
    const float* __restrict__ w2b, const float* __restrict__ b2b,
    float* __restrict__ feat)
{
    extern __shared__ float smem[];
    float* ht = smem;              // [324][68]
    float* xt = ht + 324 * 68;     // [20][20]
    float* wa = xt + 400;          // [9][64]
    float* wb = wa + 576;          // [9][64]
    float* ba = wb + 576;          // [64]

    const int tid = threadIdx.x;
    const int tx = tid & 15, ty = tid >> 4;
    const int x0 = blockIdx.x * 16, y0 = blockIdx.y * 16;
    const int b = blockIdx.z >> 1, br = blockIdx.z & 1;

    const float* in = (br ? g : x) + (size_t)b * NPIX;
    const float* wA = br ? w2a : w1a;
    const float* wB = br ? w2b : w1b;
    const float* bA = br ? b2a : b1a;
    const float* bB = br ? b2b : b1b;

    for (int t = tid; t < 576; t += 256) {
        int c = t / 9, tap = t % 9;
        wa[tap * 64 + c] = wA[t];
        wb[tap * 64 + c] = wB[t];
    }
    if (tid < 64) ba[tid] = bA[tid];

    for (int t = tid; t < 400; t += 256) {
        int r = t / 20, c = t % 20;
        int gy = y0 - 2 + r, gx = x0 - 2 + c;
        xt[t] = ((unsigned)gy < (unsigned)HH && (unsigned)gx < (unsigned)WW)
                    ? in[gy * WW + gx] : 0.f;
    }
    __syncthreads();

    for (int t = tid; t < 324 * 16; t += 256) {
        int p = t >> 4, cq = t & 15, c0 = cq * 4;
        int py = p / 18, px = p % 18;
        float a0 = ba[c0], a1 = ba[c0 + 1], a2 = ba[c0 + 2], a3 = ba[c0 + 3];
        #pragma unroll
        for (int u = 0; u < 3; u++)
            #pragma unroll
            for (int v = 0; v < 3; v++) {
                float xv = xt[(py + u) * 20 + px + v];
                int wi = (u * 3 + v) * 64 + c0;
                a0 += xv * wa[wi];
                a1 += xv * wa[wi + 1];
                a2 += xv * wa[wi + 2];
                a3 += xv * wa[wi + 3];
            }
        float* hp = &ht[p * 68 + c0];
        hp[0] = fmaxf(a0, 0.f); hp[1] = fmaxf(a1, 0.f);
        hp[2] = fmaxf(a2, 0.f); hp[3] = fmaxf(a3, 0.f);
    }
    __syncthreads();

    float acc = bB[0];
    #pragma unroll
    for (int u = 0; u < 3; u++)
        #pragma unroll
        for (int v = 0; v < 3; v++) {
            int base = ((ty + u) * 18 + (tx + v)) * 68;
            int wi = (u * 3 + v) * 64;
            #pragma unroll
            for (int cq = 0; cq < 16; cq++) {
                float4 h4 = *(const float4*)&ht[base + cq * 4];
                acc += h4.x * wb[wi + cq * 4]     + h4.y * wb[wi + cq * 4 + 1]
                     + h4.z * wb[wi + cq * 4 + 2] + h4.w * wb[wi + cq * 4 + 3];
            }
        }
    feat[((size_t)(b * 2 + br)) * NPIX + (y0 + ty) * WW + (x0 + tx)] = acc;
}

// ---------------------------------------------------------------------------
// fused head: wfa -> h1(LDS f16) -> wfb(MFMA) -> h2(LDS f16) -> wfc(MFMA)
//             -> softmax -> patch apply. One 16x16 output tile per block.
// ---------------------------------------------------------------------------
struct SmemT {
    f16   h1[400][72];   // 20x20 region, 64 ch (pad 72) : 57600 B
    f16   h2[324][72];   // 18x18 region, 64 ch          : 46656 B
    f16   Bb[96][104];   // weight chunk, 96 k (pad 104) : 19968 B
    float ft[2][484];    // feat tile 22x22 x2           : 3872 B
    float xt[576];       // x tile 24x24                 : 2304 B
    f16   wA[64][40];    // wfa packed [cout][32 k]      : 5120 B
    float bA[64];
    float bB2[64];
    float bC[96];
};  // total 136416 B

__global__ __launch_bounds__(512) void fused_head_kernel(
    const float* __restrict__ feat, const f16* __restrict__ wpA,
    const f16* __restrict__ wpB, const f16* __restrict__ wpC,
    const float* __restrict__ bfa, const float* __restrict__ bfb,
    const float* __restrict__ bfc, const float* __restrict__ x,
    float* __restrict__ out)
{
    extern __shared__ char smraw[];
    SmemT& sm = *(SmemT*)smraw;
    const int tid = threadIdx.x;
    const int wid = tid >> 6, lane = tid & 63;
    const int g = lane >> 4, cl = lane & 15;
    const int x0 = blockIdx.x * 16, y0 = blockIdx.y * 16;
    const int b = blockIdx.z;

    // ---- phase 0: stage feat tile, x tile, wfa, biases ----
    for (int t = tid; t < 968; t += 512) {
        int cin = t / 484, p = t % 484;
        int py = p / 22, px = p % 22;
        int gy = y0 - 3 + py, gx = x0 - 3 + px;
        sm.ft[cin][p] = ((unsigned)gy < (unsigned)HH && (unsigned)gx < (unsigned)WW)
            ? feat[((size_t)(b * 2 + cin)) * NPIX + gy * WW + gx] : 0.f;
    }
    for (int t = tid; t < 576; t += 512) {
        int r = t / 24, c = t % 24;
        int gy = y0 - 4 + r, gx = x0 - 4 + c;
        sm.xt[t] = ((unsigned)gy < (unsigned)HH && (unsigned)gx < (unsigned)WW)
            ? x[(size_t)b * NPIX + gy * WW + gx] : 0.f;
    }
    for (int t = tid; t < 2048; t += 512) sm.wA[t >> 5][t & 31] = wpA[t];
    if (tid < 64) sm.bA[tid] = bfa[tid];
    else if (tid < 128) sm.bB2[tid - 64] = bfb[tid - 64];
    else if (tid < 224) sm.bC[tid - 128] = (tid - 128) < 81 ? bfc[tid - 128] : 0.f;
    __syncthreads();

    // ---- phase 1: h1 = relu(conv(feat, wfa)+bfa) via MFMA, 20x20 region ----
    // A: rows = pixels (lane&15), k = g*8+j (k = cin*9+tap, K=18 pad 32)
    for (int mt = wid; mt < 25; mt += 8) {
        int p = mt * 16 + cl;
        int py = p / 20, px = p - 20 * py;
        f16x8 a;
        #pragma unroll
        for (int j = 0; j < 8; j++) {
            int k = g * 8 + j;
            float v = 0.f;
            if (k < 18) {
                int cin = k >= 9 ? 1 : 0;
                int tap = k - 9 * cin;
                int u = tap / 3, vv = tap - 3 * u;
                v = sm.ft[cin][(py + u) * 22 + px + vv];
            }
            a[j] = (f16)v;
        }
        f32x4 acc[4];
        #pragma unroll
        for (int nt = 0; nt < 4; nt++) {
            f32x4 z = {0.f, 0.f, 0.f, 0.f};
            f16x8 bb = *(const f16x8*)&sm.wA[nt * 16 + cl][g * 8];
            acc[nt] = __builtin_amdgcn_mfma_f32_16x16x32_f16(a, bb, z, 0, 0, 0);
        }
        // D: row = g*4+reg (pixel), col = cl (cout within nt group)
        #pragma unroll
        for (int nt = 0; nt < 4; nt++)
            #pragma unroll
            for (int reg = 0; reg < 4; reg++) {
                int pd = mt * 16 + g * 4 + reg;
                int pdy = pd / 20, pdx = pd - 20 * pdy;
                int gy = y0 - 2 + pdy, gx = x0 - 2 + pdx;
                // reference zero-pads h1 outside the image
                float v = ((unsigned)gy < (unsigned)HH && (unsigned)gx < (unsigned)WW)
                    ? fmaxf(acc[nt][reg] + sm.bA[nt * 16 + cl], 0.f) : 0.f;
                sm.h1[pd][nt * 16 + cl] = (f16)v;
            }
    }

    // ---- phase 2: h2 = relu(conv(h1, wfb)+bfb) via MFMA, 18x18 region ----
    f32x4 accB[3][4];
    #pragma unroll
    for (int i = 0; i < 3; i++)
        #pragma unroll
        for (int nt = 0; nt < 4; nt++) accB[i][nt] = (f32x4){0.f, 0.f, 0.f, 0.f};

    #pragma unroll 1
    for (int ch = 0; ch < 6; ch++) {
        __syncthreads();
        for (int q = tid; q < 64 * 24; q += 512) {
            int c = q / 24, qq = q - 24 * c;
            *(uint2*)&sm.Bb[c][qq * 4] =
                *(const uint2*)&wpB[c * 576 + ch * 96 + qq * 4];
        }
        __syncthreads();
        #pragma unroll
        for (int k3 = 0; k3 < 3; k3++) {
            int kk = ch * 3 + k3;
            int tap = kk >> 1, cin0 = (kk & 1) * 32;
            int u = tap / 3, v = tap - 3 * u;
            f16x8 bf[4];
            #pragma unroll
            for (int nt = 0; nt < 4; nt++)
                bf[nt] = *(const f16x8*)&sm.Bb[nt * 16 + cl][k3 * 32 + g * 8];
            #pragma unroll
            for (int i = 0; i < 3; i++) {
                int mt = wid + 8 * i;
                if (mt < 21) {
                    int p = mt * 16 + cl;
                    if (p > 323) p = 323;   // clamp pad rows (writes masked)
                    int py = p / 18, px = p - 18 * py;
                    f16x8 a = *(const f16x8*)&sm.h1[(py + u) * 20 + px + v][cin0 + g * 8];
                    #pragma unroll
                    for (int nt = 0; nt < 4; nt++)
                        accB[i][nt] = __builtin_amdgcn_mfma_f32_16x16x32_f16(
                            a, bf[nt], accB[i][nt], 0, 0, 0);
                }
            }
        }
    }
    #pragma unroll
    for (int i = 0; i < 3; i++) {
        int mt = wid + 8 * i;
        if (mt < 21) {
            #pragma unroll
            for (int nt = 0; nt < 4; nt++)
                #pragma unroll
                for (int reg = 0; reg < 4; reg++) {
                    int pd = mt * 16 + g * 4 + reg;
                    if (pd < 324) {
                        int pdy = pd / 18, pdx = pd - 18 * pdy;
                        int gy = y0 - 1 + pdy, gx = x0 - 1 + pdx;
                        float v = ((unsigned)gy < (unsigned)HH && (unsigned)gx < (unsigned)WW)
                            ? fmaxf(accB[i][nt][reg] + sm.bB2[nt * 16 + cl], 0.f) : 0.f;
                        sm.h2[pd][nt * 16 + cl] = (f16)v;
                    }
                }
        }
    }

    // ---- phase 3: logits = conv(h2, wfc)+bfc via MFMA, 16x16, 96 couts ----
    f32x4 accC[2][6];
    #pragma unroll
    for (int i = 0; i < 2; i++)
        #pragma unroll
        for (int nt = 0; nt < 6; nt++) accC[i][nt] = (f32x4){0.f, 0.f, 0.f, 0.f};

    #pragma unroll 1
    for (int ch = 0; ch < 6; ch++) {
        __syncthreads();   // also covers h2-writes -> h2-reads on first iter
        for (int q = tid; q < 96 * 24; q += 512) {
            int c = q / 24, qq = q - 24 * c;
            *(uint2*)&sm.Bb[c][qq * 4] =
                *(const uint2*)&wpC[c * 576 + ch * 96 + qq * 4];
        }
        __syncthreads();
        #pragma unroll
        for (int k3 = 0; k3 < 3; k3++) {
            int kk = ch * 3 + k3;
            int tap = kk >> 1, cin0 = (kk & 1) * 32;
            int u = tap / 3, v = tap - 3 * u;
            f16x8 bf[6];
            #pragma unroll
            for (int nt = 0; nt < 6; nt++)
                bf[nt] = *(const f16x8*)&sm.Bb[nt * 16 + cl][k3 * 32 + g * 8];
            #pragma unroll
            for (int i = 0; i < 2; i++) {
                int mt = wid * 2 + i;       // pixel row py == mt, px == cl
                f16x8 a = *(const f16x8*)&sm.h2[(mt + u) * 18 + cl + v][cin0 + g * 8];
                #pragma unroll
                for (int nt = 0; nt < 6; nt++)
                    accC[i][nt] = __builtin_amdgcn_mfma_f32_16x16x32_f16(
                        a, bf[nt], accC[i][nt], 0, 0, 0);
            }
        }
    }

    // ---- phase 4: softmax over 81 taps + apply 9x9 patch ----
    #pragma unroll
    for (int i = 0; i < 2; i++) {
        int mt = wid * 2 + i;
        #pragma unroll
        for (int reg = 0; reg < 4; reg++) {
            int py = mt, px = g * 4 + reg;   // D row = g*4+reg within tile row mt
            float val[6];
            #pragma unroll
            for (int nt = 0; nt < 6; nt++)
                val[nt] = accC[i][nt][reg] + sm.bC[nt * 16 + cl];
            if (cl != 0) val[5] = -1e30f;    // couts 81..95 invalid
            float m = val[0];
            #pragma unroll
            for (int nt = 1; nt < 6; nt++) m = fmaxf(m, val[nt]);
            #pragma unroll
            for (int d = 1; d < 16; d <<= 1) m = fmaxf(m, __shfl_xor(m, d));
            float s = 0.f, o = 0.f;
            #pragma unroll
            for (int nt = 0; nt < 6; nt++) {
                int c = nt * 16 + cl;
                int cs = c > 80 ? 80 : c;
                float e = __expf(val[nt] - m);
                s += e;
                int u9 = cs / 9, v9 = cs - 9 * u9;
                o += e * sm.xt[(py + u9) * 24 + px + v9];
            }
            #pragma unroll
            for (int d = 1; d < 16; d <<= 1) {
                s += __shfl_xor(s, d);
                o += __shfl_xor(o, d);
            }
            if (cl == 0)
                out[(size_t)b * NPIX + (y0 + py) * WW + (x0 + px)] = o / s;
        }
    }
}

// ---------------------------------------------------------------------------
extern "C" void kernel_launch(void* const* d_in, const int* in_sizes, int n_in,
                              void* d_out, int out_size, void* d_ws, size_t ws_size,
                              hipStream_t stream)
{
    const float* x   = (const float*)d_in[0];
    const float* g   = (const float*)d_in[1];
    const float* w1a = (const float*)d_in[2];  const float* b1a = (const float*)d_in[3];
    const float* w1b = (const float*)d_in[4];  const float* b1b = (const float*)d_in[5];
    const float* w2a = (const float*)d_in[6];  const float* b2a = (const float*)d_in[7];
    const float* w2b = (const float*)d_in[8];  const float* b2b = (const float*)d_in[9];
    const float* wfa = (const float*)d_in[10]; const float* bfa = (const float*)d_in[11];
    const float* wfb = (const float*)d_in[12]; const float* bfb = (const float*)d_in[13];
    const float* wfc = (const float*)d_in[14]; const float* bfc = (const float*)d_in[15];
    float* out = (float*)d_out;

    // workspace: feat fp32 [16][2][256][256], then f16 packed weights
    float* feat = (float*)d_ws;                    // 2,097,152 floats
    f16* wpA = (f16*)(feat + 2097152);             // 2048
    f16* wpB = wpA + 2048;                         // 36864
    f16* wpC = wpB + 36864;                        // 55296

    prepack_kernel<<<dim3(216), 256, 0, stream>>>(wfa, wfb, wfc, wpA, wpB, wpC);

    size_t shA = (size_t)(324 * 68 + 400 + 576 + 576 + 64) * 4;
    branch_kernel<<<dim3(16, 16, 32), 256, shA, stream>>>(
        x, g, w1a, b1a, w1b, b1b, w2a, b2a, w2b, b2b, feat);

    fused_head_kernel<<<dim3(16, 16, NB), 512, sizeof(SmemT), stream>>>(
        feat, wpA, wpB, wpC, bfa, bfb, bfc, x, out);
}